// Round 9
// baseline (201.777 us; speedup 1.0000x reference)
//
#include <hip/hip_runtime.h>
#include <hip/hip_bf16.h>

#define BTOT 32768
#define TB 32

typedef __attribute__((ext_vector_type(8))) short bhalf8;   // 8 bf16 = 4 VGPRs
typedef __attribute__((ext_vector_type(4))) float f32x4;    // MFMA acc

// R12: native cast (single v_cvt) instead of 5-op integer RNE.
static __device__ __forceinline__ unsigned short f2bf(float x) {
    __hip_bfloat16 h = __float2bfloat16(x);
    unsigned short u;
    __builtin_memcpy(&u, &h, sizeof(u));
    return u;
}
static __device__ __forceinline__ float bf2f(unsigned short s) {
    return __uint_as_float(((unsigned int)s) << 16);
}

// ---------------------------------------------------------------------------
// prep_all (R15): all weight preprocessing in one dispatch.
// Fragment layout: B-frag for (kt, nt): lane l holds
// B[k=kt*32+(l>>4)*8+j][n=nt*16+(l&15)], hi at ((nt*KT+kt)*64+l)*16+j, lo +8.
// ws: Mf2  @0       131072 B | Wef2 @131072 344064 B | Wvf2 @475136 65536 B
//     W2f  @540672  16384 B  | w3sf @557056 16384 B  | w3of @573440 32768 B
//     W1f  @606208  24576 B
// Lessons ledger:
//  R9/R11: launch_bounds implying VGPR<120 -> 64-VGPR collapse + 500MB
//          spills. (256,2) is the floor; never request more waves/EU.
//  R13/R14: scalar-GEMM VALU was the dominant removable cost (155->91us).
//  R15: cross-session clock variance +/-20%; judge by within-session counters.
//  R16: LDS 44032 allowed 3 blocks/CU but occupancy DIDN'T move: 4 blocks/CU
//       of work quantizes as 3+1 -> avg residency 2, wall unchanged.
//       Residency must DIVIDE the 4-block work quantum -> R17 targets 4.
// ---------------------------------------------------------------------------
__global__ __launch_bounds__(256) void prep_all(
        const float* __restrict__ Wk, const float* __restrict__ Wq,
        const float* __restrict__ We, const float* __restrict__ Wv,
        const float* __restrict__ W2, const float* __restrict__ w3_self,
        const float* __restrict__ w3_others, const float* __restrict__ W1,
        unsigned short* __restrict__ Mf2, unsigned short* __restrict__ Wef2,
        unsigned short* __restrict__ Wvf2, unsigned short* __restrict__ W2f,
        unsigned short* __restrict__ w3sf, unsigned short* __restrict__ w3of,
        unsigned short* __restrict__ W1f)
{
    const int blk = blockIdx.x;
    if (blk < 128) {
        // ---- fold M = Wq @ Wk^T -> Mf2 fragments (32768 threads) ----
        int tid = blk * 256 + threadIdx.x;
        int h  = tid >> 13;
        int jq = (tid >> 7) & 63;
        int j  = tid & 127;
        const float* q = Wq + (h*64 + jq)*32;
        const float* k = Wk + (h*128 + j)*32;
        float acc = 0.f;
#pragma unroll
        for (int d = 0; d < 32; d += 4) {
            float4 a = *(const float4*)(q + d);
            float4 b = *(const float4*)(k + d);
            acc += a.x*b.x + a.y*b.y + a.z*b.z + a.w*b.w;
        }
        unsigned short hi = f2bf(acc);
        unsigned short lo = f2bf(acc - bf2f(hi));
        int n  = h*128 + j;
        int kt = jq >> 5, qd = (jq >> 3) & 3, jj = jq & 7;
        int nt = n >> 4,  ln = n & 15;
        size_t base = (((nt*2 + kt)*64) + qd*16 + ln)*16;
        Mf2[base + jj]     = hi;
        Mf2[base + 8 + jj] = lo;
    } else if (blk < 464) {
        // ---- conv We (7*96*128 = 86016 threads) ----
        int tid = (blk - 128) * 256 + threadIdx.x;
        int a = tid / 12288;
        int r = tid - a*12288;
        int k = r >> 7;          // 0..95
        int n = r & 127;
        float v = (k < 82) ? We[((size_t)a*82 + k)*128 + n] : 0.f;
        unsigned short hi = f2bf(v);
        unsigned short lo = f2bf(v - bf2f(hi));
        int kt = k >> 5, qd = (k >> 3) & 3, j = k & 7;
        int nt = n >> 4, ln = n & 15;
        size_t base = (size_t)a*24576 + (((nt*3 + kt)*64) + qd*16 + ln)*16;
        Wef2[base + j]     = hi;
        Wef2[base + 8 + j] = lo;
    } else if (blk < 528) {
        // ---- conv Wv (4*128*32 = 16384 threads) ----
        int tid = (blk - 464) * 256 + threadIdx.x;
        int h = tid >> 12;
        int j = (tid >> 5) & 127;
        int d = tid & 31;
        float v = Wv[tid];
        unsigned short hi = f2bf(v);
        unsigned short lo = f2bf(v - bf2f(hi));
        int k = j, n = h*32 + d;
        int kt = k >> 5, qd = (k >> 3) & 3, jj = k & 7;
        int nt = n >> 4, ln = n & 15;
        size_t base = (((nt*4 + kt)*64) + qd*16 + ln)*16;
        Wvf2[base + jj]     = hi;
        Wvf2[base + 8 + jj] = lo;
    } else {
        // ---- conv self weights (22528 threads) ----
        int tid = (blk - 528) * 256 + threadIdx.x;
        const float* src;
        unsigned short* dst;
        int idx, KT, kmax;
        if (tid < 4096)       { src = W2;        dst = W2f;  idx = tid;         KT = 2; kmax = 64; }
        else if (tid < 8192)  { src = w3_self;   dst = w3sf; idx = tid - 4096;  KT = 2; kmax = 64; }
        else if (tid < 16384) { src = w3_others; dst = w3of; idx = tid - 8192;  KT = 4; kmax = 128; }
        else                  { src = W1;        dst = W1f;  idx = tid - 16384; KT = 3; kmax = 78; }
        int k = idx >> 6;
        int n = idx & 63;
        float v = (k < kmax) ? src[k*64 + n] : 0.f;
        unsigned short hi = f2bf(v);
        unsigned short lo = f2bf(v - bf2f(hi));
        int kt = k >> 5, qd = (k >> 3) & 3, j = k & 7;
        int nt = n >> 4, ln = n & 15;
        size_t base = (((nt*KT + kt)*64) + qd*16 + ln)*16;
        dst[base + j]     = hi;
        dst[base + 8 + j] = lo;
    }
}

// ---------------------------------------------------------------------------
// Fused critic. TB=32 rows/block, 256 threads (4 waves), 1024 blocks.
// R17 = R16 with sIn SINGLE-buffered too: LDS 44032 -> 33280 B (floor = sT)
//   => 4 blocks/CU resident (VGPR cap is also 4 at 128 VGPR) = EXACTLY the
//   4-blocks/CU work quantum -> one residency round, no straggler tail
//   (R16 lesson: residency must divide the work quantum).
// Single-sIn audit (2 barriers/agent, unchanged from R16):
//   B2(a-1)..B1(a): enc(a) reads sIn(a) [staged B1(a-1)..B2(a-1)];
//                   vals(a-1)/logits(a-1) read sEn(a-1); prefetch a+1 ->regs.
//                   NO LDS writes in this interval.
//   B1(a)..B2(a):   write sEn(a) (sEn reads ended before B1);
//                   stageIn(a+1) -> sIn (sIn reads ended before B1).
// Every LDS producer->consumer crosses a __syncthreads. 3-4 blocks/CU is the
// historical nondeterminism condition; R8's fix (stats in registers, no
// un-barriered LDS dataflow) held at 3-resident in R16 (absmax bit-stable).
// Abort criterion: absmax jump -> revert + quarantine.
// LDS 33280 B:
//   self : sXbH[32x104]@0, sXbL@6656; sX1bH[32x72]@13312, sX1bL@17920;
//          sX2bH@22528, sX2bL@27136 (ends 31744)
//   t    : sT bf16[32x520]@0..33280 (overlays; written only after the
//          internal barrier ending all sXb/sX1b/sX2b reads)
//   agent: sIn (single): H@0, L@6656 (ends 13312)
//          sEn (single): H@13312, L@22016 (ends 30720)
//   final: sOvH bf16[32x136]@0, sOvL@8704 (ends 17408), sRed f32[32x4]@17408
//          (sOvL overlaps old sEnH bytes — written only after the post-loop
//           barrier that ends all sEn reads)
// ---------------------------------------------------------------------------
__global__ __launch_bounds__(256, 2) void fused_critic(
    const float* __restrict__ state_one, const float* __restrict__ act_one,
    const float* __restrict__ state_others, const float* __restrict__ act_others,
    const float* __restrict__ b1, const float* __restrict__ b2,
    const float* __restrict__ be, const float* __restrict__ bvp,
    const float* __restrict__ Wout, const float* __restrict__ bout,
    const unsigned short* __restrict__ Mf2, const unsigned short* __restrict__ Wef2,
    const unsigned short* __restrict__ Wvf2, const unsigned short* __restrict__ W2f,
    const unsigned short* __restrict__ w3sf, const unsigned short* __restrict__ w3of,
    const unsigned short* __restrict__ W1f, float* __restrict__ out)
{
    __shared__ __align__(16) unsigned char smem[33280];
    unsigned short* sXbH  = (unsigned short*)smem;           // stride 104
    unsigned short* sXbL  = (unsigned short*)(smem + 6656);  // stride 104
    unsigned short* sX1bH = (unsigned short*)(smem + 13312); // stride 72
    unsigned short* sX1bL = (unsigned short*)(smem + 17920); // stride 72
    unsigned short* sX2bH = (unsigned short*)(smem + 22528); // stride 72
    unsigned short* sX2bL = (unsigned short*)(smem + 27136); // stride 72
    unsigned short* sT    = (unsigned short*)smem;           // stride 520
    unsigned short* sInH  = (unsigned short*)smem;           // stride 104
    unsigned short* sInL  = (unsigned short*)(smem + 6656);  // stride 104
    unsigned short* sEnH  = (unsigned short*)(smem + 13312); // stride 136
    unsigned short* sEnL  = (unsigned short*)(smem + 22016); // stride 136
    unsigned short* sOvH  = (unsigned short*)smem;           // stride 136
    unsigned short* sOvL  = (unsigned short*)(smem + 8704);  // stride 136
    float*          sRed  = (float*)(smem + 17408);          // [32][4]

    const int t  = threadIdx.x;
    const int b0 = blockIdx.x * TB;
    const int w  = t >> 6;        // wave = head / self-col-tile
    const int l  = t & 63;
    const int m  = l & 15;        // MFMA A row / C col
    const int qd = l >> 4;        // quad

    const int act_r = t >> 3, act_c = t & 7;

    // staging helper: split-bf16 convert regs -> sIn (cols 0..81)
    auto stageIn = [&](const float4& vA, const float4& vB, const float* av) {
        const int r0 = t >> 4, c4 = (t & 15) << 2;
        ushort4 h4, l4;
        h4.x = f2bf(vA.x); l4.x = f2bf(vA.x - bf2f(h4.x));
        h4.y = f2bf(vA.y); l4.y = f2bf(vA.y - bf2f(h4.y));
        h4.z = f2bf(vA.z); l4.z = f2bf(vA.z - bf2f(h4.z));
        h4.w = f2bf(vA.w); l4.w = f2bf(vA.w - bf2f(h4.w));
        *(ushort4*)(sInH + r0*104 + c4) = h4;
        *(ushort4*)(sInL + r0*104 + c4) = l4;
        h4.x = f2bf(vB.x); l4.x = f2bf(vB.x - bf2f(h4.x));
        h4.y = f2bf(vB.y); l4.y = f2bf(vB.y - bf2f(h4.y));
        h4.z = f2bf(vB.z); l4.z = f2bf(vB.z - bf2f(h4.z));
        h4.w = f2bf(vB.w); l4.w = f2bf(vB.w - bf2f(h4.w));
        *(ushort4*)(sInH + (r0+16)*104 + c4) = h4;
        *(ushort4*)(sInL + (r0+16)*104 + c4) = l4;
        if (act_c < 6) {
#pragma unroll
            for (int e = 0; e < 3; ++e) {
                float v = av[e];
                unsigned short hh = f2bf(v);
                sInH[act_r*104 + 64 + act_c*3 + e] = hh;
                sInL[act_r*104 + 64 + act_c*3 + e] = f2bf(v - bf2f(hh));
            }
        }
    };

    // ---- stage self input [32 x 96] split bf16 (cols 78..95 zero) ----
    {
        const int r0 = t >> 4, c4 = (t & 15) << 2;
        float4 vA = *(const float4*)(state_one + (size_t)(b0 + r0)*64 + c4);
        float4 vB = *(const float4*)(state_one + (size_t)(b0 + r0 + 16)*64 + c4);
        ushort4 h4, l4;
        h4.x = f2bf(vA.x); l4.x = f2bf(vA.x - bf2f(h4.x));
        h4.y = f2bf(vA.y); l4.y = f2bf(vA.y - bf2f(h4.y));
        h4.z = f2bf(vA.z); l4.z = f2bf(vA.z - bf2f(h4.z));
        h4.w = f2bf(vA.w); l4.w = f2bf(vA.w - bf2f(h4.w));
        *(ushort4*)(sXbH + r0*104 + c4) = h4;
        *(ushort4*)(sXbL + r0*104 + c4) = l4;
        h4.x = f2bf(vB.x); l4.x = f2bf(vB.x - bf2f(h4.x));
        h4.y = f2bf(vB.y); l4.y = f2bf(vB.y - bf2f(h4.y));
        h4.z = f2bf(vB.z); l4.z = f2bf(vB.z - bf2f(h4.z));
        h4.w = f2bf(vB.w); l4.w = f2bf(vB.w - bf2f(h4.w));
        *(ushort4*)(sXbH + (r0+16)*104 + c4) = h4;
        *(ushort4*)(sXbL + (r0+16)*104 + c4) = l4;
        // act cols 64..79 (78,79 zero)
#pragma unroll
        for (int e = 0; e < 2; ++e) {
            int cc = act_c*2 + e;
            float v = (cc < 14) ? act_one[(size_t)(b0 + act_r)*14 + cc] : 0.f;
            unsigned short hh = f2bf(v);
            sXbH[act_r*104 + 64 + cc] = hh;
            sXbL[act_r*104 + 64 + cc] = f2bf(v - bf2f(hh));
        }
        // pad cols 80..95
        for (int f = t; f < TB*16; f += 256) {
            int r = f >> 4, c = 80 + (f & 15);
            sXbH[r*104 + c] = 0;
            sXbL[r*104 + c] = 0;
        }
    }
    __syncthreads();

    // ---- phase 1 (MFMA): x1 = relu(x @ W1 + b1) -> split bf16 LDS ----
    {
        f32x4 acc1[2] = {};
#pragma unroll
        for (int kt = 0; kt < 3; ++kt) {
            bhalf8 ah0 = *(const bhalf8*)(sXbH + m*104      + kt*32 + qd*8);
            bhalf8 ah1 = *(const bhalf8*)(sXbH + (16+m)*104 + kt*32 + qd*8);
            bhalf8 al0 = *(const bhalf8*)(sXbL + m*104      + kt*32 + qd*8);
            bhalf8 al1 = *(const bhalf8*)(sXbL + (16+m)*104 + kt*32 + qd*8);
            const unsigned short* bp = W1f + ((w*3 + kt)*64 + l)*16;
            bhalf8 bh = *(const bhalf8*)(bp);
            bhalf8 bl = *(const bhalf8*)(bp + 8);
            acc1[0] = __builtin_amdgcn_mfma_f32_16x16x32_bf16(ah0, bh, acc1[0], 0, 0, 0);
            acc1[1] = __builtin_amdgcn_mfma_f32_16x16x32_bf16(ah1, bh, acc1[1], 0, 0, 0);
            acc1[0] = __builtin_amdgcn_mfma_f32_16x16x32_bf16(ah0, bl, acc1[0], 0, 0, 0);
            acc1[1] = __builtin_amdgcn_mfma_f32_16x16x32_bf16(ah1, bl, acc1[1], 0, 0, 0);
            acc1[0] = __builtin_amdgcn_mfma_f32_16x16x32_bf16(al0, bh, acc1[0], 0, 0, 0);
            acc1[1] = __builtin_amdgcn_mfma_f32_16x16x32_bf16(al1, bh, acc1[1], 0, 0, 0);
        }
        int col = w*16 + m;
        float b1c = b1[col];
#pragma unroll
        for (int rt = 0; rt < 2; ++rt)
#pragma unroll
            for (int r = 0; r < 4; ++r) {
                float e = fmaxf(acc1[rt][r] + b1c, 0.f);
                int row = rt*16 + qd*4 + r;
                unsigned short hh = f2bf(e);
                sX1bH[row*72 + col] = hh;
                sX1bL[row*72 + col] = f2bf(e - bf2f(hh));
            }
    }
    __syncthreads();

    // ---- phase 2 (MFMA): x2 = relu(x1 @ W2 + b2) -> split bf16 LDS ----
    {
        f32x4 acc2[2] = {};
#pragma unroll
        for (int kt = 0; kt < 2; ++kt) {
            bhalf8 ah0 = *(const bhalf8*)(sX1bH + m*72      + kt*32 + qd*8);
            bhalf8 ah1 = *(const bhalf8*)(sX1bH + (16+m)*72 + kt*32 + qd*8);
            bhalf8 al0 = *(const bhalf8*)(sX1bL + m*72      + kt*32 + qd*8);
            bhalf8 al1 = *(const bhalf8*)(sX1bL + (16+m)*72 + kt*32 + qd*8);
            const unsigned short* bp = W2f + ((w*2 + kt)*64 + l)*16;
            bhalf8 bh = *(const bhalf8*)(bp);
            bhalf8 bl = *(const bhalf8*)(bp + 8);
            acc2[0] = __builtin_amdgcn_mfma_f32_16x16x32_bf16(ah0, bh, acc2[0], 0, 0, 0);
            acc2[1] = __builtin_amdgcn_mfma_f32_16x16x32_bf16(ah1, bh, acc2[1], 0, 0, 0);
            acc2[0] = __builtin_amdgcn_mfma_f32_16x16x32_bf16(ah0, bl, acc2[0], 0, 0, 0);
            acc2[1] = __builtin_amdgcn_mfma_f32_16x16x32_bf16(ah1, bl, acc2[1], 0, 0, 0);
            acc2[0] = __builtin_amdgcn_mfma_f32_16x16x32_bf16(al0, bh, acc2[0], 0, 0, 0);
            acc2[1] = __builtin_amdgcn_mfma_f32_16x16x32_bf16(al1, bh, acc2[1], 0, 0, 0);
        }
        int col = w*16 + m;
        float b2c = b2[col];
#pragma unroll
        for (int rt = 0; rt < 2; ++rt)
#pragma unroll
            for (int r = 0; r < 4; ++r) {
                float e = fmaxf(acc2[rt][r] + b2c, 0.f);
                int row = rt*16 + qd*4 + r;
                unsigned short hh = f2bf(e);
                sX2bH[row*72 + col] = hh;
                sX2bL[row*72 + col] = f2bf(e - bf2f(hh));
            }
    }
    __syncthreads();

    // ---- phase 3 (MFMA): x3a = x2 @ w3_self, kept in registers ----
    f32x4 x3a[2] = {};
    {
#pragma unroll
        for (int kt = 0; kt < 2; ++kt) {
            bhalf8 ah0 = *(const bhalf8*)(sX2bH + m*72      + kt*32 + qd*8);
            bhalf8 ah1 = *(const bhalf8*)(sX2bH + (16+m)*72 + kt*32 + qd*8);
            bhalf8 al0 = *(const bhalf8*)(sX2bL + m*72      + kt*32 + qd*8);
            bhalf8 al1 = *(const bhalf8*)(sX2bL + (16+m)*72 + kt*32 + qd*8);
            const unsigned short* bp = w3sf + ((w*2 + kt)*64 + l)*16;
            bhalf8 bh = *(const bhalf8*)(bp);
            bhalf8 bl = *(const bhalf8*)(bp + 8);
            x3a[0] = __builtin_amdgcn_mfma_f32_16x16x32_bf16(ah0, bh, x3a[0], 0, 0, 0);
            x3a[1] = __builtin_amdgcn_mfma_f32_16x16x32_bf16(ah1, bh, x3a[1], 0, 0, 0);
            x3a[0] = __builtin_amdgcn_mfma_f32_16x16x32_bf16(ah0, bl, x3a[0], 0, 0, 0);
            x3a[1] = __builtin_amdgcn_mfma_f32_16x16x32_bf16(ah1, bl, x3a[1], 0, 0, 0);
            x3a[0] = __builtin_amdgcn_mfma_f32_16x16x32_bf16(al0, bh, x3a[0], 0, 0, 0);
            x3a[1] = __builtin_amdgcn_mfma_f32_16x16x32_bf16(al1, bh, x3a[1], 0, 0, 0);
        }
    }

    // ---- phase 4: t = x1 @ M, split 3-term MFMA, -> sT bf16 ----
    {
        f32x4 tacc[2][8] = {};
#pragma unroll
        for (int kt = 0; kt < 2; ++kt) {
            bhalf8 ah0 = *(const bhalf8*)(sX1bH + m*72      + kt*32 + qd*8);
            bhalf8 ah1 = *(const bhalf8*)(sX1bH + (16+m)*72 + kt*32 + qd*8);
            bhalf8 al0 = *(const bhalf8*)(sX1bL + m*72      + kt*32 + qd*8);
            bhalf8 al1 = *(const bhalf8*)(sX1bL + (16+m)*72 + kt*32 + qd*8);
#pragma unroll
            for (int nt2 = 0; nt2 < 8; ++nt2) {
                int nt = w*8 + nt2;
                const unsigned short* bp = Mf2 + ((nt*2 + kt)*64 + l)*16;
                bhalf8 bh = *(const bhalf8*)(bp);
                bhalf8 bl = *(const bhalf8*)(bp + 8);
                tacc[0][nt2] = __builtin_amdgcn_mfma_f32_16x16x32_bf16(ah0, bh, tacc[0][nt2], 0, 0, 0);
                tacc[1][nt2] = __builtin_amdgcn_mfma_f32_16x16x32_bf16(ah1, bh, tacc[1][nt2], 0, 0, 0);
                tacc[0][nt2] = __builtin_amdgcn_mfma_f32_16x16x32_bf16(ah0, bl, tacc[0][nt2], 0, 0, 0);
                tacc[1][nt2] = __builtin_amdgcn_mfma_f32_16x16x32_bf16(ah1, bl, tacc[1][nt2], 0, 0, 0);
                tacc[0][nt2] = __builtin_amdgcn_mfma_f32_16x16x32_bf16(al0, bh, tacc[0][nt2], 0, 0, 0);
                tacc[1][nt2] = __builtin_amdgcn_mfma_f32_16x16x32_bf16(al1, bh, tacc[1][nt2], 0, 0, 0);
            }
        }
        __syncthreads();   // ALL reads of sXb/sX1b/sX2b done before sT overlays
#pragma unroll
        for (int rt = 0; rt < 2; ++rt)
#pragma unroll
            for (int nt2 = 0; nt2 < 8; ++nt2)
#pragma unroll
                for (int r = 0; r < 4; ++r)
                    sT[(rt*16 + qd*4 + r)*520 + w*128 + nt2*16 + m] =
                        f2bf(tacc[rt][nt2][r]);
    }
    __syncthreads();

    // ---- load t as B-FRAGMENT registers (logits MFMA), rows m / 16+m ----
    bhalf8 tB0[4], tB1[4];
    {
#pragma unroll
        for (int kt = 0; kt < 4; ++kt) {
            tB0[kt] = *(const bhalf8*)(sT + m*520      + w*128 + kt*32 + qd*8);
            tB1[kt] = *(const bhalf8*)(sT + (16+m)*520 + w*128 + kt*32 + qd*8);
        }
    }
    __syncthreads();   // sT region free for sIn/sEn

    // zero-pad sIn cols 82..95 once (80,81 are act cols, staged every agent)
    for (int f = t; f < TB*16; f += 256) {
        int r = f >> 4, c = f & 15;
        if (c >= 2) {
            sInH[r*104 + 80 + c] = 0;
            sInL[r*104 + 80 + c] = 0;
        }
    }
    // stage agent 0 into the single sIn buffer
    {
        const float* sa = state_others + (size_t)b0 * 64;
        float4 vA = *(const float4*)(sa + t*4);
        float4 vB = *(const float4*)(sa + t*4 + 1024);
        float av[3] = {0.f, 0.f, 0.f};
        if (act_c < 6) {
            const float* aa = act_others + (size_t)(b0 + act_r)*18 + act_c*3;
            av[0] = aa[0]; av[1] = aa[1]; av[2] = aa[2];
        }
        stageIn(vA, vB, av);
    }
    __syncthreads();   // sIn (agent 0) ready

    const float bv0 = bvp[w*32 + m];
    const float bv1 = bvp[w*32 + 16 + m];
    f32x4 o4[2][2] = {};
    float mR = -1e30f, sR = 0.f;

    // diag extraction constants: logit row b_l sits in lane src, lacc[b_l>>4]
    const int nsel = l & 15;
    const int srcl = ((nsel >> 2) << 4) | nsel;

    float4 pfA, pfB; float pfa[3] = {0.f, 0.f, 0.f};

    for (int a = 0; a < 7; ++a) {
        // ---- issue next agent's HBM loads (regs); hides under enc ----
        if (a < 6) {
            const float* sa = state_others + ((size_t)(a+1)*BTOT + b0)*64;
            pfA = *(const float4*)(sa + t*4);
            pfB = *(const float4*)(sa + t*4 + 1024);
            if (act_c < 6) {
                const float* aa = act_others
                    + ((size_t)(a+1)*BTOT + b0 + act_r)*18 + act_c*3;
                pfa[0] = aa[0]; pfa[1] = aa[1]; pfa[2] = aa[2];
            }
        }
        float be0 = be[a*128 + 32*w + m];
        float be1 = be[a*128 + 32*w + 16 + m];

        // ---- enc(a) = inp @ We_a -> eacc regs (same interval as vals(a-1))
        f32x4 eacc[2][2] = {};
#pragma unroll
        for (int kt = 0; kt < 3; ++kt) {
            bhalf8 ah0 = *(const bhalf8*)(sInH + m*104      + kt*32 + qd*8);
            bhalf8 ah1 = *(const bhalf8*)(sInH + (16+m)*104 + kt*32 + qd*8);
            bhalf8 al0 = *(const bhalf8*)(sInL + m*104      + kt*32 + qd*8);
            bhalf8 al1 = *(const bhalf8*)(sInL + (16+m)*104 + kt*32 + qd*8);
#pragma unroll
            for (int nt2 = 0; nt2 < 2; ++nt2) {
                int nt = 2*w + nt2;
                const unsigned short* bp =
                    Wef2 + (size_t)a*24576 + ((nt*3 + kt)*64 + l)*16;
                bhalf8 bh = *(const bhalf8*)(bp);
                bhalf8 bl = *(const bhalf8*)(bp + 8);
                eacc[0][nt2] = __builtin_amdgcn_mfma_f32_16x16x32_bf16(ah0, bh, eacc[0][nt2], 0, 0, 0);
                eacc[1][nt2] = __builtin_amdgcn_mfma_f32_16x16x32_bf16(ah1, bh, eacc[1][nt2], 0, 0, 0);
                eacc[0][nt2] = __builtin_amdgcn_mfma_f32_16x16x32_bf16(ah0, bl, eacc[0][nt2], 0, 0, 0);
                eacc[1][nt2] = __builtin_amdgcn_mfma_f32_16x16x32_bf16(ah1, bl, eacc[1][nt2], 0, 0, 0);
                eacc[0][nt2] = __builtin_amdgcn_mfma_f32_16x16x32_bf16(al0, bh, eacc[0][nt2], 0, 0, 0);
                eacc[1][nt2] = __builtin_amdgcn_mfma_f32_16x16x32_bf16(al1, bh, eacc[1][nt2], 0, 0, 0);
            }
        }

        // ---- B1: vals(a-1) reads of sEn + enc(a) reads of sIn done ----
        __syncthreads();

        // ---- write sEn(a) (relu+bias, split); stage sIn(a+1) ----
        {
#pragma unroll
            for (int rt = 0; rt < 2; ++rt)
#pragma unroll
                for (int nt2 = 0; nt2 < 2; ++nt2) {
                    float bb = nt2 ? be1 : be0;
#pragma unroll
                    for (int r = 0; r < 4; ++r) {
                        float e = fmaxf(eacc[rt][nt2][r] + bb, 0.f);
                        int row = rt*16 + qd*4 + r;
                        int col = 32*w + nt2*16 + m;
                        unsigned short hh = f2bf(e);
                        sEnH[row*136 + col] = hh;
                        sEnL[row*136 + col] = f2bf(e - bf2f(hh));
                    }
                }
        }
        if (a < 6) stageIn(pfA, pfB, pfa);

        // ---- B2: sEn(a) and sIn(a+1) visible to all waves ----
        __syncthreads();

        // ---- fused vals + logits MFMA loop (shared A-fragments) ----
        f32x4 vacc[2][2] = {};
        f32x4 lacc0 = {}, lacc1 = {};
#pragma unroll
        for (int kt = 0; kt < 4; ++kt) {
            bhalf8 ah0 = *(const bhalf8*)(sEnH + m*136      + kt*32 + qd*8);
            bhalf8 ah1 = *(const bhalf8*)(sEnH + (16+m)*136 + kt*32 + qd*8);
            bhalf8 al0 = *(const bhalf8*)(sEnL + m*136      + kt*32 + qd*8);
            bhalf8 al1 = *(const bhalf8*)(sEnL + (16+m)*136 + kt*32 + qd*8);
#pragma unroll
            for (int nt2 = 0; nt2 < 2; ++nt2) {
                int nt = 2*w + nt2;
                const unsigned short* bp = Wvf2 + ((nt*4 + kt)*64 + l)*16;
                bhalf8 bh = *(const bhalf8*)(bp);
                bhalf8 bl = *(const bhalf8*)(bp + 8);
                vacc[0][nt2] = __builtin_amdgcn_mfma_f32_16x16x32_bf16(ah0, bh, vacc[0][nt2], 0, 0, 0);
                vacc[1][nt2] = __builtin_amdgcn_mfma_f32_16x16x32_bf16(ah1, bh, vacc[1][nt2], 0, 0, 0);
                vacc[0][nt2] = __builtin_amdgcn_mfma_f32_16x16x32_bf16(ah0, bl, vacc[0][nt2], 0, 0, 0);
                vacc[1][nt2] = __builtin_amdgcn_mfma_f32_16x16x32_bf16(ah1, bl, vacc[1][nt2], 0, 0, 0);
                vacc[0][nt2] = __builtin_amdgcn_mfma_f32_16x16x32_bf16(al0, bh, vacc[0][nt2], 0, 0, 0);
                vacc[1][nt2] = __builtin_amdgcn_mfma_f32_16x16x32_bf16(al1, bh, vacc[1][nt2], 0, 0, 0);
            }
            // logits diag: C[r][n] = enc_rows @ t_rows^T (B-frag from regs)
            lacc0 = __builtin_amdgcn_mfma_f32_16x16x32_bf16(ah0, tB0[kt], lacc0, 0, 0, 0);
            lacc0 = __builtin_amdgcn_mfma_f32_16x16x32_bf16(al0, tB0[kt], lacc0, 0, 0, 0);
            lacc1 = __builtin_amdgcn_mfma_f32_16x16x32_bf16(ah1, tB1[kt], lacc1, 0, 0, 0);
            lacc1 = __builtin_amdgcn_mfma_f32_16x16x32_bf16(al1, tB1[kt], lacc1, 0, 0, 0);
        }

        // ---- extract diag -> stats (registers + wave-collective only) ----
        float alpha, pp;
        {
            float e01 = (l & 1) ? lacc0[1] : lacc0[0];
            float e23 = (l & 1) ? lacc0[3] : lacc0[2];
            float d0  = (l & 2) ? e23 : e01;
            float f01 = (l & 1) ? lacc1[1] : lacc1[0];
            float f23 = (l & 1) ? lacc1[3] : lacc1[2];
            float d1  = (l & 2) ? f23 : f01;
            float g0 = __shfl(d0, srcl);
            float g1 = __shfl(d1, srcl);
            float part = (l & 16) ? g1 : g0;
            float lg = part * 0.17677669529663687f;   // 1/sqrt(32)
            float mn = fmaxf(mR, lg);
            alpha = __expf(mR - mn);
            pp    = __expf(lg - mn);
            sR = sR*alpha + pp;
            mR = mn;
        }

        // ---- online accumulate o4 ----
        {
#pragma unroll
            for (int rt = 0; rt < 2; ++rt)
#pragma unroll
                for (int r = 0; r < 4; ++r) {
                    int row = rt*16 + qd*4 + r;
                    float al = __shfl(alpha, row);
                    float p  = __shfl(pp, row);
#pragma unroll
                    for (int nt2 = 0; nt2 < 2; ++nt2) {
                        float bb = nt2 ? bv1 : bv0;
                        o4[rt][nt2][r] = o4[rt][nt2][r]*al
                                       + p*fmaxf(vacc[rt][nt2][r] + bb, 0.f);
                    }
                }
        }
    }
    __syncthreads();   // all sEn/sIn reads done; sOv overlays sIn + sEnH head

    // ---- normalize, write ov as SPLIT bf16 (A-operand for final MFMA) ----
    {
        float rinv = 1.0f / sR;
#pragma unroll
        for (int rt = 0; rt < 2; ++rt)
#pragma unroll
            for (int r = 0; r < 4; ++r) {
                int row = rt*16 + qd*4 + r;
                float inv = __shfl(rinv, row);
#pragma unroll
                for (int nt2 = 0; nt2 < 2; ++nt2) {
                    float v = o4[rt][nt2][r]*inv;
                    int col = 32*w + nt2*16 + m;
                    unsigned short hh = f2bf(v);
                    sOvH[row*136 + col] = hh;
                    sOvL[row*136 + col] = f2bf(v - bf2f(hh));
                }
            }
    }
    __syncthreads();

    // ---- final (MFMA): x3a += ov @ w3_others; out = relu(x3a).Wout + bout
    {
#pragma unroll
        for (int kt = 0; kt < 4; ++kt) {
            bhalf8 ah0 = *(const bhalf8*)(sOvH + m*136      + kt*32 + qd*8);
            bhalf8 ah1 = *(const bhalf8*)(sOvH + (16+m)*136 + kt*32 + qd*8);
            bhalf8 al0 = *(const bhalf8*)(sOvL + m*136      + kt*32 + qd*8);
            bhalf8 al1 = *(const bhalf8*)(sOvL + (16+m)*136 + kt*32 + qd*8);
            const unsigned short* bp = w3of + ((w*4 + kt)*64 + l)*16;
            bhalf8 bh = *(const bhalf8*)(bp);
            bhalf8 bl = *(const bhalf8*)(bp + 8);
            x3a[0] = __builtin_amdgcn_mfma_f32_16x16x32_bf16(ah0, bh, x3a[0], 0, 0, 0);
            x3a[1] = __builtin_amdgcn_mfma_f32_16x16x32_bf16(ah1, bh, x3a[1], 0, 0, 0);
            x3a[0] = __builtin_amdgcn_mfma_f32_16x16x32_bf16(ah0, bl, x3a[0], 0, 0, 0);
            x3a[1] = __builtin_amdgcn_mfma_f32_16x16x32_bf16(ah1, bl, x3a[1], 0, 0, 0);
            x3a[0] = __builtin_amdgcn_mfma_f32_16x16x32_bf16(al0, bh, x3a[0], 0, 0, 0);
            x3a[1] = __builtin_amdgcn_mfma_f32_16x16x32_bf16(al1, bh, x3a[1], 0, 0, 0);
        }
        // lane holds x3[row=rt*16+qd*4+r][col=16w+m]; relu, *Wout, reduce m
        float wo = Wout[w*16 + m];
#pragma unroll
        for (int rt = 0; rt < 2; ++rt)
#pragma unroll
            for (int r = 0; r < 4; ++r) {
                float p = fmaxf(x3a[rt][r], 0.f) * wo;
                p += __shfl_xor(p, 1);
                p += __shfl_xor(p, 2);
                p += __shfl_xor(p, 4);
                p += __shfl_xor(p, 8);
                if (m == 0)
                    sRed[(rt*16 + qd*4 + r)*4 + w] = p;
            }
    }
    __syncthreads();
    if (t < 32)
        out[b0 + t] = sRed[t*4+0] + sRed[t*4+1] + sRed[t*4+2] + sRed[t*4+3]
                    + bout[0];
}

extern "C" void kernel_launch(void* const* d_in, const int* in_sizes, int n_in,
                              void* d_out, int out_size, void* d_ws, size_t ws_size,
                              hipStream_t stream) {
    (void)in_sizes; (void)n_in; (void)out_size; (void)ws_size;
    const float* state_one    = (const float*)d_in[0];
    const float* act_one      = (const float*)d_in[1];
    const float* state_others = (const float*)d_in[2];
    const float* act_others   = (const float*)d_in[3];
    const float* W1           = (const float*)d_in[4];
    const float* b1           = (const float*)d_in[5];
    const float* W2           = (const float*)d_in[6];
    const float* b2           = (const float*)d_in[7];
    const float* w3_self      = (const float*)d_in[8];
    const float* We           = (const float*)d_in[9];
    const float* be           = (const float*)d_in[10];
    const float* Wk           = (const float*)d_in[11];
    const float* Wq           = (const float*)d_in[12];
    const float* Wv           = (const float*)d_in[13];
    const float* bv           = (const float*)d_in[14];
    const float* w3_others    = (const float*)d_in[15];
    const float* Wout         = (const float*)d_in[16];
    const float* bout         = (const float*)d_in[17];
    float* out = (float*)d_out;

    unsigned short* Mf2  = (unsigned short*)d_ws;                    // 131072 B
    unsigned short* Wef2 = (unsigned short*)((char*)d_ws + 131072);  // 344064 B
    unsigned short* Wvf2 = (unsigned short*)((char*)d_ws + 475136);  // 65536 B
    unsigned short* W2f  = (unsigned short*)((char*)d_ws + 540672);  // 16384 B
    unsigned short* w3sf = (unsigned short*)((char*)d_ws + 557056);  // 16384 B
    unsigned short* w3of = (unsigned short*)((char*)d_ws + 573440);  // 32768 B
    unsigned short* W1f  = (unsigned short*)((char*)d_ws + 606208);  // 24576 B

    prep_all<<<616, 256, 0, stream>>>(Wk, Wq, We, Wv, W2, w3_self, w3_others,
                                      W1, Mf2, Wef2, Wvf2, W2f, w3sf, w3of, W1f);
    fused_critic<<<BTOT/TB, 256, 0, stream>>>(
        state_one, act_one, state_others, act_others,
        b1, b2, be, bv, Wout, bout,
        Mf2, Wef2, Wvf2, W2f, w3sf, w3of, W1f, out);
}